// Round 12
// baseline (113.404 us; speedup 1.0000x reference)
//
#include <hip/hip_runtime.h>

#define BATCH 2
#define SDIM 2048
#define HDIM 1024
#define NHEADS 16
#define HEADD 64
#define WIN 1024

typedef __bf16 bf16x8 __attribute__((ext_vector_type(8)));
typedef __bf16 bf16x4 __attribute__((ext_vector_type(4)));
typedef float f32x4 __attribute__((ext_vector_type(4)));
typedef unsigned short u16x8 __attribute__((ext_vector_type(8)));

__device__ __forceinline__ unsigned short bf16_rne(float f) {
    union { float f; unsigned u; } x; x.f = f;
    unsigned r = x.u + 0x7fffu + ((x.u >> 16) & 1u);
    return (unsigned short)(r >> 16);
}

__device__ __forceinline__ void gload_lds16(const unsigned short* g, unsigned short* l) {
    __builtin_amdgcn_global_load_lds(
        (const __attribute__((address_space(1))) void*)g,
        (__attribute__((address_space(3))) void*)l, 16, 0, 0);
}

// ---------------- fused prep: f32->bf16 converts + RoPE table ----------------
__global__ __launch_bounds__(256) void prep_kernel(
    const float* __restrict__ hs, const float* __restrict__ wq, const float* __restrict__ wk,
    const float* __restrict__ wv, const float* __restrict__ wo,
    unsigned short* __restrict__ Xb, unsigned short* __restrict__ Wqkv,
    unsigned short* __restrict__ Wob, float2* __restrict__ cstab)
{
    int i = blockIdx.x * 256 + threadIdx.x;
    if (i < 2097152) {
        const float* src; unsigned short* dst; int off;
        if (i < 1048576)      { src = hs; dst = Xb;             off = i; }
        else if (i < 1310720) { src = wq; dst = Wqkv;           off = i - 1048576; }
        else if (i < 1572864) { src = wk; dst = Wqkv + 1048576; off = i - 1310720; }
        else if (i < 1835008) { src = wv; dst = Wqkv + 2097152; off = i - 1572864; }
        else                  { src = wo; dst = Wob;            off = i - 1835008; }
        float4 v = reinterpret_cast<const float4*>(src)[off];
        ushort4 r;
        r.x = bf16_rne(v.x); r.y = bf16_rne(v.y); r.z = bf16_rne(v.z); r.w = bf16_rne(v.w);
        reinterpret_cast<ushort4*>(dst)[off] = r;
    } else {
        int j = i - 2097152;                 // < 65536
        int p = j >> 5, f = j & 31;
        float inv = (float)pow(10000.0, -(double)f / 32.0);
        float ang = (float)p * inv;
        cstab[j] = make_float2(cosf(ang), sinf(ang));
    }
}

// ---------------- 128x128 bf16 GEMM mainloop ----------------
// 3-buffer ring, counted vmcnt(4) (never 0 mid-loop). Swizzle verified conflict-free
// (SQ_LDS_BANK_CONFLICT = 0). Callers supply XCD-chunked m0/n0 for L2 residency.
__device__ __forceinline__ void mfma_gemm_128(
    const unsigned short* __restrict__ A,
    const unsigned short* __restrict__ Bm,
    int m0, int n0, int tid,
    unsigned short* lA, unsigned short* lB,
    f32x4 acc[4][4])
{
    const int K = 1024;
    const int BUF = 128 * 32;
    int lane = tid & 63, wid = tid >> 6;
    int wm = wid >> 1, wn = wid & 1;
    int lane15 = lane & 15, lhi = lane >> 4;
    int lrow = lane >> 2;
    int swz = (lane & 3) ^ ((lane >> 3) & 3);
    const unsigned short* ga0 = A  + (long)(m0 + wid * 32      + lrow) * K + swz * 8;
    const unsigned short* ga1 = A  + (long)(m0 + wid * 32 + 16 + lrow) * K + swz * 8;
    const unsigned short* gb0 = Bm + (long)(n0 + wid * 32      + lrow) * K + swz * 8;
    const unsigned short* gb1 = Bm + (long)(n0 + wid * 32 + 16 + lrow) * K + swz * 8;
    unsigned short* la0 = lA + (wid * 32)      * 32;
    unsigned short* la1 = lA + (wid * 32 + 16) * 32;
    unsigned short* lb0 = lB + (wid * 32)      * 32;
    unsigned short* lb1 = lB + (wid * 32 + 16) * 32;
    int ru = (lhi ^ ((lane15 >> 1) & 3)) * 8;

#define STAGE_G(boff, kt) \
    gload_lds16(ga0 + (kt) * 32, la0 + (boff)); \
    gload_lds16(ga1 + (kt) * 32, la1 + (boff)); \
    gload_lds16(gb0 + (kt) * 32, lb0 + (boff)); \
    gload_lds16(gb1 + (kt) * 32, lb1 + (boff));

#define COMPUTE_G(off) { \
    bf16x8 af[4], bfr[4]; \
    _Pragma("unroll") \
    for (int f = 0; f < 4; f++) { \
        af[f]  = *(const bf16x8*)&lA[(off) + (wm * 64 + f * 16 + lane15) * 32 + ru]; \
        bfr[f] = *(const bf16x8*)&lB[(off) + (wn * 64 + f * 16 + lane15) * 32 + ru]; \
    } \
    _Pragma("unroll") \
    for (int i = 0; i < 4; i++) \
        _Pragma("unroll") \
        for (int j = 0; j < 4; j++) \
            acc[i][j] = __builtin_amdgcn_mfma_f32_16x16x32_bf16(af[i], bfr[j], acc[i][j], 0, 0, 0); \
}

#define WAITB(n) \
    asm volatile("s_waitcnt vmcnt(" #n ")" ::: "memory"); \
    __builtin_amdgcn_s_barrier(); \
    asm volatile("" ::: "memory");

    STAGE_G(0, 0);
    STAGE_G(BUF, 1);
    #pragma unroll 1
    for (int t = 0; t < 30; t += 3) {
        WAITB(4);
        STAGE_G(2 * BUF, t + 2);
        COMPUTE_G(0);
        WAITB(4);
        STAGE_G(0, t + 3);
        COMPUTE_G(BUF);
        WAITB(4);
        STAGE_G(BUF, t + 4);
        COMPUTE_G(2 * BUF);
    }
    WAITB(4);
    COMPUTE_G(0);
    WAITB(0);
    COMPUTE_G(BUF);

#undef STAGE_G
#undef COMPUTE_G
#undef WAITB
}

// ---------------- fused QKV projection + bias + RoPE + V-transpose ----------------
// 3-buffer ring (R6/R10 measured 48 us), XCD-chunked grid, fused V^T epilogue.
__global__ __launch_bounds__(256) void gemm_qkv_kernel(
    const unsigned short* __restrict__ Xb,
    const unsigned short* __restrict__ Wb,
    const float* __restrict__ bq, const float* __restrict__ bk, const float* __restrict__ bv,
    const float2* __restrict__ cstab,
    unsigned short* __restrict__ qbuf, unsigned short* __restrict__ kbuf, unsigned short* __restrict__ vbuf)
{
    __shared__ __align__(16) unsigned short lA[3 * 128 * 32];
    __shared__ __align__(16) unsigned short lB[3 * 128 * 32];
    int tid = threadIdx.x;
    int lane = tid & 63, wid = tid >> 6;
    int wm = wid >> 1, wn = wid & 1;
    int lane15 = lane & 15, lhi = lane >> 4;
    int bid = blockIdx.x;
    int xcd = bid & 7, j5 = bid >> 3;          // 96 blocks per XCD
    int m0 = (xcd * 4 + (j5 & 3)) * 128;       // 4 X panels per XCD (L2-resident)
    int n0 = (j5 >> 2) * 128;                  // 24 W strips, streamed n-outer
    f32x4 acc[4][4];
    #pragma unroll
    for (int i = 0; i < 4; i++)
        #pragma unroll
        for (int j = 0; j < 4; j++)
            acc[i][j] = (f32x4){0.f, 0.f, 0.f, 0.f};

    mfma_gemm_128(Xb, Wb, m0, n0, tid, lA, lB, acc);

    int proj = n0 >> 10;                       // 0=q 1=k 2=v
    int ncol0 = (n0 & 1023) + wn * 64;
    int h = ncol0 >> 6;
    int bb = m0 >> 11, s0r = m0 & (SDIM - 1);
    if (proj == 2) {
        // V: bias-add -> swizzled LDS [d][s] tile (b64-packed) -> coalesced V^T stores
        const float* bias = bv;
        __syncthreads();                       // mainloop LDS reads complete in all waves
        #pragma unroll
        for (int fm = 0; fm < 4; fm++) {
            int sl0 = wm * 64 + fm * 16 + lhi * 4;
            #pragma unroll
            for (int fn = 0; fn < 4; fn++) {
                int dl = wn * 64 + fn * 16 + lane15;
                float bia = bias[(n0 & 1023) + dl];
                bf16x4 c;
                #pragma unroll
                for (int reg = 0; reg < 4; reg++)
                    c[reg] = (__bf16)(acc[fm][fn][reg] + bia);
                *(bf16x4*)&lA[dl * 128 + (sl0 ^ ((dl & 7) * 8))] = c;
            }
        }
        __syncthreads();
        int h0 = (n0 & 1023) >> 6;
        #pragma unroll
        for (int it = 0; it < 8; it++) {
            int d = it * 16 + (tid >> 4);
            int s8 = tid & 15;
            u16x8 valv = *(const u16x8*)&lA[d * 128 + ((s8 ^ (d & 7)) * 8)];
            int hh = h0 + (d >> 6);
            *(u16x8*)&vbuf[((long)(bb * NHEADS + hh) * HEADD + (d & 63)) * SDIM + s0r + s8 * 8] = valv;
        }
    } else {
        unsigned short* dst = proj == 0 ? qbuf : kbuf;
        const float* bias = proj == 0 ? bq : bk;
        #pragma unroll
        for (int fm = 0; fm < 4; fm++) {
            #pragma unroll
            for (int reg = 0; reg < 4; reg++) {
                int m = m0 + wm * 64 + fm * 16 + lhi * 4 + reg;
                int s = m & (SDIM - 1);
                long base = ((long)(bb * NHEADS + h) * SDIM + s) * HEADD;
                #pragma unroll
                for (int fn = 0; fn < 2; fn++) {
                    int j = fn * 16 + lane15;
                    float lo = acc[fm][fn][reg]     + bias[ncol0 + j];
                    float hi = acc[fm][fn + 2][reg] + bias[ncol0 + 32 + j];
                    float2 cs = cstab[s * 32 + j];
                    float rl = lo * cs.x - hi * cs.y;
                    float rh = hi * cs.x + lo * cs.y;
                    if (proj == 0) { rl *= 0.125f; rh *= 0.125f; }
                    dst[base + j]      = bf16_rne(rl);
                    dst[base + 32 + j] = bf16_rne(rh);
                }
            }
        }
    }
}

// ---------------- flash attention: QBLK=128, global_load_lds K/V ring ----------------
// q/k: [B,NH,S,HD] bf16 (q pre-scaled by 1/8). vT: [B,NH,HD,S]. ctx out: [B,S,NH,HD] bf16.
// K/V tiles: linear [64][64] LDS, mod-8 XOR unit swizzle (pre-swizzled global source,
// swizzled read; rule #21). 2-buffer ring, counted vmcnt(2) steady-state (aq loads are
// older in the vmcnt FIFO, so counts stay exact).
__global__ __launch_bounds__(512) void attn_kernel(
    const unsigned short* __restrict__ qb,
    const unsigned short* __restrict__ kbf,
    const unsigned short* __restrict__ vtb,
    unsigned short* __restrict__ ctxb)
{
    const int TBUF = 64 * 64;                 // elements per K or V tile buffer
    __shared__ __align__(16) unsigned short Kl[2 * TBUF];   // 16 KB
    __shared__ __align__(16) unsigned short Vl[2 * TBUF];   // 16 KB
    __shared__ __align__(16) unsigned short Pl[8][16 * 72]; // 18.4 KB
    int tid = threadIdx.x, lane = tid & 63, wid = tid >> 6;   // 8 waves
    int lane15 = lane & 15, lhi = lane >> 4;

    int slot = blockIdx.x;            // 0..511
    int xcd = slot & 7;
    int pos = slot >> 3;              // 0..63
    int hb32 = xcd + 8 * (pos >> 4);  // 0..31
    int h = hb32 & 15, b = hb32 >> 4;
    int qt = 15 - (pos & 15);
    int q0b = qt * 128;
    int qw = q0b + wid * 16;          // this wave's 16 q-rows

    long hb = (long)(b * NHEADS + h) * SDIM * HEADD;
    const unsigned short* qptr = qb + hb;
    const unsigned short* kptr = kbf + hb;
    const unsigned short* vt   = vtb + hb;
    unsigned short* Pw = Pl[wid];

    bf16x8 aq0 = *(const bf16x8*)&qptr[(qw + lane15) * HEADD + lhi * 8];
    bf16x8 aq1 = *(const bf16x8*)&qptr[(qw + lane15) * HEADD + 32 + lhi * 8];

    f32x4 acc[4];
    #pragma unroll
    for (int f = 0; f < 4; f++) acc[f] = (f32x4){0.f, 0.f, 0.f, 0.f};
    float rs = 0.f;                   // lane-local partial sum for q = qw + lane15

    int t0 = q0b - (WIN - 1);
    int kb0 = t0 > 0 ? (t0 >> 6) : 0;
    int kbl = (q0b + 127) >> 6;       // >= kb0 + 1 always

    // staging geometry: thread stages one 16B unit of K and one of V per tile.
    int srow = (wid * 8) + ((lane >> 3) & 7);   // 0..63 (row within tile)
    int p8 = lane & 7;                          // phys unit
    int u8 = p8 ^ (srow & 7);                   // logical (global) unit
    const unsigned short* kg = kptr + (long)srow * HEADD + u8 * 8;   // + kbase*64 per tile
    const unsigned short* vg = vt + (long)srow * SDIM + u8 * 8;      // + kbase per tile
    unsigned short* lK = Kl + srow * 64 + p8 * 8;                    // linear: base + lane*16B
    unsigned short* lV = Vl + srow * 64 + p8 * 8;

    // prologue: tiles kb0, kb0+1 (kbl >= kb0+1 guaranteed)
    gload_lds16(kg + (long)kb0 * 64 * HEADD, lK);
    gload_lds16(vg + kb0 * 64, lV);
    gload_lds16(kg + (long)(kb0 + 1) * 64 * HEADD, lK + TBUF);
    gload_lds16(vg + (kb0 + 1) * 64, lV + TBUF);

    int cur = 0;
    for (int kblk = kb0; kblk <= kbl; kblk++) {
        if (kblk < kbl) { asm volatile("s_waitcnt vmcnt(2)" ::: "memory"); }
        else            { asm volatile("s_waitcnt vmcnt(0)" ::: "memory"); }
        __syncthreads();              // tile kblk landed for all waves
        int kbase = kblk * 64;
        bool active = !(kbase + 63 < qw - (WIN - 1)) && !(kbase > qw + 15);
        if (active) {
            const unsigned short* Kc = Kl + cur * TBUF;
            const unsigned short* Vc = Vl + cur * TBUF;
            bool full = (kbase + 63 <= qw) && (qw + 15 - kbase < WIN);
            f32x4 S[4];
            #pragma unroll
            for (int fk = 0; fk < 4; fk++) {
                int row = fk * 16 + lane15;
                int r7 = (row & 7);
                bf16x8 bk0 = *(const bf16x8*)&Kc[row * 64 + ((lhi ^ r7) * 8)];
                bf16x8 bk1 = *(const bf16x8*)&Kc[row * 64 + (((4 + lhi) ^ r7) * 8)];
                f32x4 s = (f32x4){0.f, 0.f, 0.f, 0.f};
                s = __builtin_amdgcn_mfma_f32_16x16x32_bf16(bk0, aq0, s, 0, 0, 0);
                s = __builtin_amdgcn_mfma_f32_16x16x32_bf16(bk1, aq1, s, 0, 0, 0);
                S[fk] = s;
            }
            if (!full) {
                int q = qw + lane15;
                #pragma unroll
                for (int fk = 0; fk < 4; fk++)
                    #pragma unroll
                    for (int r = 0; r < 4; r++) {
                        int k = kbase + fk * 16 + lhi * 4 + r;
                        bool ok = (k <= q) && (q - k < WIN);
                        if (!ok) S[fk][r] = -1e30f;
                    }
            }
            #pragma unroll
            for (int fk = 0; fk < 4; fk++) {
                bf16x4 c;
                #pragma unroll
                for (int r = 0; r < 4; r++) {
                    float pv = __expf(S[fk][r]);
                    rs += pv;
                    c[r] = (__bf16)pv;
                }
                *(bf16x4*)&Pw[lane15 * 72 + fk * 16 + lhi * 4] = c;
            }
            #pragma unroll
            for (int ks = 0; ks < 2; ks++) {
                bf16x8 pa = *(const bf16x8*)&Pw[lane15 * 72 + ks * 32 + lhi * 8];
                #pragma unroll
                for (int fd = 0; fd < 4; fd++) {
                    int row = fd * 16 + lane15;
                    bf16x8 bv2 = *(const bf16x8*)&Vc[row * 64 + (((ks * 4 + lhi) ^ (row & 7)) * 8)];
                    acc[fd] = __builtin_amdgcn_mfma_f32_16x16x32_bf16(pa, bv2, acc[fd], 0, 0, 0);
                }
            }
        }
        __syncthreads();              // all waves done reading buf cur
        if (kblk + 2 <= kbl) {
            gload_lds16(kg + (long)(kblk + 2) * 64 * HEADD, lK + cur * TBUF);
            gload_lds16(vg + (kblk + 2) * 64, lV + cur * TBUF);
        }
        cur ^= 1;
    }
    rs += __shfl_xor(rs, 16);
    rs += __shfl_xor(rs, 32);
    float linv[4];
    #pragma unroll
    for (int r = 0; r < 4; r++)
        linv[r] = 1.0f / __shfl(rs, lhi * 4 + r);
    #pragma unroll
    for (int fd = 0; fd < 4; fd++)
        #pragma unroll
        for (int r = 0; r < 4; r++) {
            int q = qw + lhi * 4 + r;
            int d = fd * 16 + lane15;
            ctxb[(((long)b * SDIM + q) * NHEADS + h) * HEADD + d] = bf16_rne(acc[fd][r] * linv[r]);
        }
}

// ---------------- output projection: out = ctx @ wo^T + bo (f32 out) ----------------
// 1-D grid 256, XCD-chunked: 4 m-strips x 8 n-strips per XCD.
__global__ __launch_bounds__(256) void gemm_o_kernel(
    const unsigned short* __restrict__ Ab,
    const unsigned short* __restrict__ Wb,
    const float* __restrict__ bo,
    float* __restrict__ out)
{
    __shared__ __align__(16) unsigned short lA[3 * 128 * 32];
    __shared__ __align__(16) unsigned short lB[3 * 128 * 32];
    int tid = threadIdx.x;
    int lane = tid & 63, wid = tid >> 6;
    int wm = wid >> 1, wn = wid & 1;
    int lane15 = lane & 15, lhi = lane >> 4;
    int bid = blockIdx.x;
    int xcd = bid & 7, j5 = bid >> 3;          // 32 blocks per XCD
    int m0 = (xcd * 4 + (j5 & 3)) * 128;
    int n0 = (j5 >> 2) * 128;
    f32x4 acc[4][4];
    #pragma unroll
    for (int i = 0; i < 4; i++)
        #pragma unroll
        for (int j = 0; j < 4; j++)
            acc[i][j] = (f32x4){0.f, 0.f, 0.f, 0.f};

    mfma_gemm_128(Ab, Wb, m0, n0, tid, lA, lB, acc);

    #pragma unroll
    for (int fm = 0; fm < 4; fm++)
        #pragma unroll
        for (int reg = 0; reg < 4; reg++) {
            int m = m0 + wm * 64 + fm * 16 + lhi * 4 + reg;
            #pragma unroll
            for (int fn = 0; fn < 4; fn++) {
                int n = n0 + wn * 64 + fn * 16 + lane15;
                out[(long)m * HDIM + n] = acc[fm][fn][reg] + bo[n];
            }
        }
}

extern "C" void kernel_launch(void* const* d_in, const int* in_sizes, int n_in,
                              void* d_out, int out_size, void* d_ws, size_t ws_size,
                              hipStream_t stream) {
    const float* hs = (const float*)d_in[0];
    const float* wq = (const float*)d_in[2];
    const float* bq = (const float*)d_in[3];
    const float* wk = (const float*)d_in[4];
    const float* bk = (const float*)d_in[5];
    const float* wv = (const float*)d_in[6];
    const float* bv = (const float*)d_in[7];
    const float* wo = (const float*)d_in[8];
    const float* bo = (const float*)d_in[9];
    float* out = (float*)d_out;

    char* ws = (char*)d_ws;
    unsigned short* Xb    = (unsigned short*)(ws);                    // 8 MB
    unsigned short* Wqkv  = (unsigned short*)(ws + (8l  << 20));      // 6 MB
    unsigned short* Wob   = (unsigned short*)(ws + (14l << 20));      // 2 MB
    float2*         cstab = (float2*)        (ws + (16l << 20));      // 512 KB
    unsigned short* qbuf  = (unsigned short*)(ws + (17l << 20));      // 8 MB
    unsigned short* kbuf  = (unsigned short*)(ws + (25l << 20));      // 8 MB
    unsigned short* vbuf  = (unsigned short*)(ws + (33l << 20));      // 8 MB  (holds V^T [B,NH,HD,S])
    unsigned short* ctxb  = (unsigned short*)(ws + (41l << 20));      // 8 MB

    prep_kernel<<<8448, 256, 0, stream>>>(hs, wq, wk, wv, wo, Xb, Wqkv, Wob, cstab);
    gemm_qkv_kernel<<<768, 256, 0, stream>>>(Xb, Wqkv, bq, bk, bv, cstab, qbuf, kbuf, vbuf);
    attn_kernel<<<512, 512, 0, stream>>>(qbuf, kbuf, vbuf, ctxb);
    gemm_o_kernel<<<256, 256, 0, stream>>>(ctxb, Wob, bo, out);
}

// Round 13
// 101.902 us; speedup vs baseline: 1.1129x; 1.1129x over previous
//
#include <hip/hip_runtime.h>

#define BATCH 2
#define SDIM 2048
#define HDIM 1024
#define NHEADS 16
#define HEADD 64
#define WIN 1024

typedef __bf16 bf16x8 __attribute__((ext_vector_type(8)));
typedef __bf16 bf16x4 __attribute__((ext_vector_type(4)));
typedef float f32x4 __attribute__((ext_vector_type(4)));
typedef unsigned short u16x8 __attribute__((ext_vector_type(8)));

__device__ __forceinline__ unsigned short bf16_rne(float f) {
    union { float f; unsigned u; } x; x.f = f;
    unsigned r = x.u + 0x7fffu + ((x.u >> 16) & 1u);
    return (unsigned short)(r >> 16);
}

__device__ __forceinline__ void gload_lds16(const unsigned short* g, unsigned short* l) {
    __builtin_amdgcn_global_load_lds(
        (const __attribute__((address_space(1))) void*)g,
        (__attribute__((address_space(3))) void*)l, 16, 0, 0);
}

// ---------------- fused prep: f32->bf16 converts + RoPE table ----------------
__global__ __launch_bounds__(256) void prep_kernel(
    const float* __restrict__ hs, const float* __restrict__ wq, const float* __restrict__ wk,
    const float* __restrict__ wv, const float* __restrict__ wo,
    unsigned short* __restrict__ Xb, unsigned short* __restrict__ Wqkv,
    unsigned short* __restrict__ Wob, float2* __restrict__ cstab)
{
    int i = blockIdx.x * 256 + threadIdx.x;
    if (i < 2097152) {
        const float* src; unsigned short* dst; int off;
        if (i < 1048576)      { src = hs; dst = Xb;             off = i; }
        else if (i < 1310720) { src = wq; dst = Wqkv;           off = i - 1048576; }
        else if (i < 1572864) { src = wk; dst = Wqkv + 1048576; off = i - 1310720; }
        else if (i < 1835008) { src = wv; dst = Wqkv + 2097152; off = i - 1572864; }
        else                  { src = wo; dst = Wob;            off = i - 1835008; }
        float4 v = reinterpret_cast<const float4*>(src)[off];
        ushort4 r;
        r.x = bf16_rne(v.x); r.y = bf16_rne(v.y); r.z = bf16_rne(v.z); r.w = bf16_rne(v.w);
        reinterpret_cast<ushort4*>(dst)[off] = r;
    } else {
        int j = i - 2097152;                 // < 65536
        int p = j >> 5, f = j & 31;
        float inv = (float)pow(10000.0, -(double)f / 32.0);
        float ang = (float)p * inv;
        cstab[j] = make_float2(cosf(ang), sinf(ang));
    }
}

// ---------------- 128x128 bf16 GEMM mainloop (used by gemm_o) ----------------
// 3-buffer ring, counted vmcnt(4). Swizzle verified conflict-free (SQ_LDS_BANK_CONFLICT=0).
__device__ __forceinline__ void mfma_gemm_128(
    const unsigned short* __restrict__ A,
    const unsigned short* __restrict__ Bm,
    int m0, int n0, int tid,
    unsigned short* lA, unsigned short* lB,
    f32x4 acc[4][4])
{
    const int K = 1024;
    const int BUF = 128 * 32;
    int lane = tid & 63, wid = tid >> 6;
    int wm = wid >> 1, wn = wid & 1;
    int lane15 = lane & 15, lhi = lane >> 4;
    int lrow = lane >> 2;
    int swz = (lane & 3) ^ ((lane >> 3) & 3);
    const unsigned short* ga0 = A  + (long)(m0 + wid * 32      + lrow) * K + swz * 8;
    const unsigned short* ga1 = A  + (long)(m0 + wid * 32 + 16 + lrow) * K + swz * 8;
    const unsigned short* gb0 = Bm + (long)(n0 + wid * 32      + lrow) * K + swz * 8;
    const unsigned short* gb1 = Bm + (long)(n0 + wid * 32 + 16 + lrow) * K + swz * 8;
    unsigned short* la0 = lA + (wid * 32)      * 32;
    unsigned short* la1 = lA + (wid * 32 + 16) * 32;
    unsigned short* lb0 = lB + (wid * 32)      * 32;
    unsigned short* lb1 = lB + (wid * 32 + 16) * 32;
    int ru = (lhi ^ ((lane15 >> 1) & 3)) * 8;

#define STAGE_G(boff, kt) \
    gload_lds16(ga0 + (kt) * 32, la0 + (boff)); \
    gload_lds16(ga1 + (kt) * 32, la1 + (boff)); \
    gload_lds16(gb0 + (kt) * 32, lb0 + (boff)); \
    gload_lds16(gb1 + (kt) * 32, lb1 + (boff));

#define COMPUTE_G(off) { \
    bf16x8 af[4], bfr[4]; \
    _Pragma("unroll") \
    for (int f = 0; f < 4; f++) { \
        af[f]  = *(const bf16x8*)&lA[(off) + (wm * 64 + f * 16 + lane15) * 32 + ru]; \
        bfr[f] = *(const bf16x8*)&lB[(off) + (wn * 64 + f * 16 + lane15) * 32 + ru]; \
    } \
    _Pragma("unroll") \
    for (int i = 0; i < 4; i++) \
        _Pragma("unroll") \
        for (int j = 0; j < 4; j++) \
            acc[i][j] = __builtin_amdgcn_mfma_f32_16x16x32_bf16(af[i], bfr[j], acc[i][j], 0, 0, 0); \
}

#define WAITB(n) \
    asm volatile("s_waitcnt vmcnt(" #n ")" ::: "memory"); \
    __builtin_amdgcn_s_barrier(); \
    asm volatile("" ::: "memory");

    STAGE_G(0, 0);
    STAGE_G(BUF, 1);
    #pragma unroll 1
    for (int t = 0; t < 30; t += 3) {
        WAITB(4);
        STAGE_G(2 * BUF, t + 2);
        COMPUTE_G(0);
        WAITB(4);
        STAGE_G(0, t + 3);
        COMPUTE_G(BUF);
        WAITB(4);
        STAGE_G(BUF, t + 4);
        COMPUTE_G(2 * BUF);
    }
    WAITB(4);
    COMPUTE_G(0);
    WAITB(0);
    COMPUTE_G(BUF);

#undef STAGE_G
#undef COMPUTE_G
#undef WAITB
}

// ---------------- fused QKV projection + bias + RoPE + V-transpose (R11 exact) ----------------
// 2-buffer ring (32 KB LDS): stage t+2 into buf(t) after compute barrier; vmcnt(4) counted,
// never drains mid-loop. V blocks write V^T directly via a 32 KB XOR-swizzled LDS transpose
// tile (reuses the full staging smem) -> vtrans kernel deleted.
__global__ __launch_bounds__(256) void gemm_qkv_kernel(
    const unsigned short* __restrict__ Xb,
    const unsigned short* __restrict__ Wb,
    const float* __restrict__ bq, const float* __restrict__ bk, const float* __restrict__ bv,
    const float2* __restrict__ cstab,
    unsigned short* __restrict__ qbuf, unsigned short* __restrict__ kbuf, unsigned short* __restrict__ vbuf)
{
    const int K = 1024;
    const int BUF = 128 * 32;
    __shared__ __align__(16) unsigned short smem[4 * 128 * 32];   // 32 KB: lA 2 bufs | lB 2 bufs
    unsigned short* lA = smem;
    unsigned short* lB = smem + 2 * BUF;
    int tid = threadIdx.x;
    int lane = tid & 63, wid = tid >> 6;
    int wm = wid >> 1, wn = wid & 1;
    int lane15 = lane & 15, lhi = lane >> 4;
    int bid = blockIdx.x;
    int xcd = bid & 7, j5 = bid >> 3;          // 96 blocks per XCD
    int m0 = (xcd * 4 + (j5 & 3)) * 128;       // 4 X panels per XCD (L2-resident)
    int n0 = (j5 >> 2) * 128;                  // 24 W strips, streamed n-outer
    int lrow = lane >> 2;
    int swz = (lane & 3) ^ ((lane >> 3) & 3);
    const unsigned short* ga0 = Xb + (long)(m0 + wid * 32      + lrow) * K + swz * 8;
    const unsigned short* ga1 = Xb + (long)(m0 + wid * 32 + 16 + lrow) * K + swz * 8;
    const unsigned short* gb0 = Wb + (long)(n0 + wid * 32      + lrow) * K + swz * 8;
    const unsigned short* gb1 = Wb + (long)(n0 + wid * 32 + 16 + lrow) * K + swz * 8;
    unsigned short* la0 = lA + (wid * 32)      * 32;
    unsigned short* la1 = lA + (wid * 32 + 16) * 32;
    unsigned short* lb0 = lB + (wid * 32)      * 32;
    unsigned short* lb1 = lB + (wid * 32 + 16) * 32;
    int ru = (lhi ^ ((lane15 >> 1) & 3)) * 8;

    f32x4 acc[4][4];
    #pragma unroll
    for (int i = 0; i < 4; i++)
        #pragma unroll
        for (int j = 0; j < 4; j++)
            acc[i][j] = (f32x4){0.f, 0.f, 0.f, 0.f};

#define STAGE_Q(boff, kt) \
    gload_lds16(ga0 + (kt) * 32, la0 + (boff)); \
    gload_lds16(ga1 + (kt) * 32, la1 + (boff)); \
    gload_lds16(gb0 + (kt) * 32, lb0 + (boff)); \
    gload_lds16(gb1 + (kt) * 32, lb1 + (boff));

#define COMPUTE_Q(off) { \
    bf16x8 af[4], bfr[4]; \
    _Pragma("unroll") \
    for (int f = 0; f < 4; f++) { \
        af[f]  = *(const bf16x8*)&lA[(off) + (wm * 64 + f * 16 + lane15) * 32 + ru]; \
        bfr[f] = *(const bf16x8*)&lB[(off) + (wn * 64 + f * 16 + lane15) * 32 + ru]; \
    } \
    _Pragma("unroll") \
    for (int i = 0; i < 4; i++) \
        _Pragma("unroll") \
        for (int j = 0; j < 4; j++) \
            acc[i][j] = __builtin_amdgcn_mfma_f32_16x16x32_bf16(af[i], bfr[j], acc[i][j], 0, 0, 0); \
}

#define WAITQ(n) \
    asm volatile("s_waitcnt vmcnt(" #n ")" ::: "memory"); \
    __builtin_amdgcn_s_barrier(); \
    asm volatile("" ::: "memory");

    STAGE_Q(0, 0);
    STAGE_Q(BUF, 1);
    #pragma unroll 1
    for (int t = 0; t < 30; t += 2) {
        WAITQ(4);                       // tile t landed; t+1 in flight
        COMPUTE_Q(0);
        __builtin_amdgcn_s_barrier();   // all waves done reading buf0
        STAGE_Q(0, t + 2);
        WAITQ(4);                       // tile t+1 landed; t+2 in flight
        COMPUTE_Q(BUF);
        __builtin_amdgcn_s_barrier();   // all waves done reading buf1
        STAGE_Q(BUF, t + 3);
    }
    WAITQ(4);                           // tile 30 landed
    COMPUTE_Q(0);
    WAITQ(0);                           // tile 31 landed (only final drain)
    COMPUTE_Q(BUF);

#undef STAGE_Q
#undef COMPUTE_Q
#undef WAITQ

    int proj = n0 >> 10;                       // 0=q 1=k 2=v
    int ncol0 = (n0 & 1023) + wn * 64;
    int h = ncol0 >> 6;
    int bb = m0 >> 11, s0r = m0 & (SDIM - 1);  // block is within one batch (128 | 2048)
    if (proj == 2) {
        // V: bias-add -> swizzled LDS [d][s] tile (32 KB, full smem) -> coalesced V^T stores
        const float* bias = bv;
        __syncthreads();                       // mainloop LDS reads complete in all waves
        #pragma unroll
        for (int fm = 0; fm < 4; fm++)
            #pragma unroll
            for (int reg = 0; reg < 4; reg++) {
                int sl = wm * 64 + fm * 16 + lhi * 4 + reg;      // s within tile
                #pragma unroll
                for (int fn = 0; fn < 4; fn++) {
                    int dl = wn * 64 + fn * 16 + lane15;         // d within 128 (2 heads)
                    float v = acc[fm][fn][reg] + bias[(n0 & 1023) + dl];
                    smem[dl * 128 + (sl ^ ((dl & 7) * 8))] = bf16_rne(v);
                }
            }
        __syncthreads();
        int h0 = (n0 & 1023) >> 6;
        #pragma unroll
        for (int it = 0; it < 8; it++) {
            int d = it * 16 + (tid >> 4);
            int s8 = tid & 15;
            u16x8 valv = *(const u16x8*)&smem[d * 128 + ((s8 ^ (d & 7)) * 8)];
            int hh = h0 + (d >> 6);
            *(u16x8*)&vbuf[((long)(bb * NHEADS + hh) * HEADD + (d & 63)) * SDIM + s0r + s8 * 8] = valv;
        }
    } else {
        unsigned short* dst = proj == 0 ? qbuf : kbuf;
        const float* bias = proj == 0 ? bq : bk;
        #pragma unroll
        for (int fm = 0; fm < 4; fm++) {
            #pragma unroll
            for (int reg = 0; reg < 4; reg++) {
                int m = m0 + wm * 64 + fm * 16 + lhi * 4 + reg;
                int s = m & (SDIM - 1);
                long base = ((long)(bb * NHEADS + h) * SDIM + s) * HEADD;
                #pragma unroll
                for (int fn = 0; fn < 2; fn++) {
                    int j = fn * 16 + lane15;
                    float lo = acc[fm][fn][reg]     + bias[ncol0 + j];
                    float hi = acc[fm][fn + 2][reg] + bias[ncol0 + 32 + j];
                    float2 cs = cstab[s * 32 + j];
                    float rl = lo * cs.x - hi * cs.y;
                    float rh = hi * cs.x + lo * cs.y;
                    if (proj == 0) { rl *= 0.125f; rh *= 0.125f; }
                    dst[base + j]      = bf16_rne(rl);
                    dst[base + 32 + j] = bf16_rne(rh);
                }
            }
        }
    }
}

// ---------------- flash attention: QBLK=128 (8 waves x 16 rows), no-max softmax ----------------
// q/k: [B,NH,S,HD] bf16 (q pre-scaled by 1/8). vT: [B,NH,HD,S]. ctx out: [B,S,NH,HD] bf16.
// R11 structure + T5 setprio around MFMA clusters.
__global__ __launch_bounds__(512) void attn_kernel(
    const unsigned short* __restrict__ qb,
    const unsigned short* __restrict__ kbf,
    const unsigned short* __restrict__ vtb,
    unsigned short* __restrict__ ctxb)
{
    __shared__ __align__(16) unsigned short Kl[64 * 72];
    __shared__ __align__(16) unsigned short Vl[64 * 72];   // rows = d, cols = s
    __shared__ __align__(16) unsigned short Pl[8][16 * 72];
    int tid = threadIdx.x, lane = tid & 63, wid = tid >> 6;   // 8 waves
    int lane15 = lane & 15, lhi = lane >> 4;

    int slot = blockIdx.x;            // 0..511
    int xcd = slot & 7;
    int pos = slot >> 3;              // 0..63
    int hb32 = xcd + 8 * (pos >> 4);  // 0..31
    int h = hb32 & 15, b = hb32 >> 4;
    int qt = 15 - (pos & 15);
    int q0b = qt * 128;
    int qw = q0b + wid * 16;          // this wave's 16 q-rows

    long hb = (long)(b * NHEADS + h) * SDIM * HEADD;
    const unsigned short* qptr = qb + hb;
    const unsigned short* kptr = kbf + hb;
    const unsigned short* vt   = vtb + hb;
    unsigned short* Pw = Pl[wid];

    bf16x8 aq0 = *(const bf16x8*)&qptr[(qw + lane15) * HEADD + lhi * 8];
    bf16x8 aq1 = *(const bf16x8*)&qptr[(qw + lane15) * HEADD + 32 + lhi * 8];

    f32x4 acc[4];
    #pragma unroll
    for (int f = 0; f < 4; f++) acc[f] = (f32x4){0.f, 0.f, 0.f, 0.f};
    float rs = 0.f;                   // lane-local partial sum for q = qw + lane15

    int t0 = q0b - (WIN - 1);
    int kb0 = t0 > 0 ? (t0 >> 6) : 0;
    int kbl = (q0b + 127) >> 6;       // = 2*qt + 1
    int srow = tid >> 3;              // 0..63
    int sc = (tid & 7) * 8;           // 16 B per thread

    u16x8 kr = *(const u16x8*)&kptr[(kb0 * 64 + srow) * HEADD + sc];
    u16x8 vr = *(const u16x8*)&vt[(long)srow * SDIM + kb0 * 64 + sc];

    for (int kblk = kb0; kblk <= kbl; kblk++) {
        int kbase = kblk * 64;
        __syncthreads();
        *(u16x8*)&Kl[srow * 72 + sc] = kr;
        *(u16x8*)&Vl[srow * 72 + sc] = vr;
        __syncthreads();
        if (kblk < kbl) {
            int nb = (kblk + 1) * 64;
            kr = *(const u16x8*)&kptr[(nb + srow) * HEADD + sc];
            vr = *(const u16x8*)&vt[(long)srow * SDIM + nb + sc];
        }
        if (kbase + 63 < qw - (WIN - 1)) continue;
        if (kbase > qw + 15) continue;

        bool full = (kbase + 63 <= qw) && (qw + 15 - kbase < WIN);
        f32x4 S[4];
        __builtin_amdgcn_s_setprio(1);
        #pragma unroll
        for (int fk = 0; fk < 4; fk++) {
            bf16x8 bk0 = *(const bf16x8*)&Kl[(fk * 16 + lane15) * 72 + lhi * 8];
            bf16x8 bk1 = *(const bf16x8*)&Kl[(fk * 16 + lane15) * 72 + 32 + lhi * 8];
            f32x4 s = (f32x4){0.f, 0.f, 0.f, 0.f};
            s = __builtin_amdgcn_mfma_f32_16x16x32_bf16(bk0, aq0, s, 0, 0, 0);
            s = __builtin_amdgcn_mfma_f32_16x16x32_bf16(bk1, aq1, s, 0, 0, 0);
            S[fk] = s;
        }
        __builtin_amdgcn_s_setprio(0);
        if (!full) {
            int q = qw + lane15;
            #pragma unroll
            for (int fk = 0; fk < 4; fk++)
                #pragma unroll
                for (int r = 0; r < 4; r++) {
                    int k = kbase + fk * 16 + lhi * 4 + r;
                    bool ok = (k <= q) && (q - k < WIN);
                    if (!ok) S[fk][r] = -1e30f;
                }
        }
        #pragma unroll
        for (int fk = 0; fk < 4; fk++) {
            bf16x4 c;
            #pragma unroll
            for (int r = 0; r < 4; r++) {
                float p = __expf(S[fk][r]);
                rs += p;
                c[r] = (__bf16)p;
            }
            *(bf16x4*)&Pw[lane15 * 72 + fk * 16 + lhi * 4] = c;
        }
        __builtin_amdgcn_s_setprio(1);
        #pragma unroll
        for (int ks = 0; ks < 2; ks++) {
            bf16x8 pa = *(const bf16x8*)&Pw[lane15 * 72 + ks * 32 + lhi * 8];
            #pragma unroll
            for (int fd = 0; fd < 4; fd++) {
                bf16x8 bv2 = *(const bf16x8*)&Vl[(fd * 16 + lane15) * 72 + ks * 32 + lhi * 8];
                acc[fd] = __builtin_amdgcn_mfma_f32_16x16x32_bf16(pa, bv2, acc[fd], 0, 0, 0);
            }
        }
        __builtin_amdgcn_s_setprio(0);
    }
    rs += __shfl_xor(rs, 16);
    rs += __shfl_xor(rs, 32);
    float linv[4];
    #pragma unroll
    for (int r = 0; r < 4; r++)
        linv[r] = 1.0f / __shfl(rs, lhi * 4 + r);
    #pragma unroll
    for (int fd = 0; fd < 4; fd++)
        #pragma unroll
        for (int r = 0; r < 4; r++) {
            int q = qw + lhi * 4 + r;
            int d = fd * 16 + lane15;
            ctxb[(((long)b * SDIM + q) * NHEADS + h) * HEADD + d] = bf16_rne(acc[fd][r] * linv[r]);
        }
}

// ---------------- output projection: out = ctx @ wo^T + bo (f32 out) ----------------
// 1-D grid 256, XCD-chunked: 4 m-strips x 8 n-strips per XCD.
__global__ __launch_bounds__(256) void gemm_o_kernel(
    const unsigned short* __restrict__ Ab,
    const unsigned short* __restrict__ Wb,
    const float* __restrict__ bo,
    float* __restrict__ out)
{
    __shared__ __align__(16) unsigned short lA[3 * 128 * 32];
    __shared__ __align__(16) unsigned short lB[3 * 128 * 32];
    int tid = threadIdx.x;
    int lane = tid & 63, wid = tid >> 6;
    int wm = wid >> 1, wn = wid & 1;
    int lane15 = lane & 15, lhi = lane >> 4;
    int bid = blockIdx.x;
    int xcd = bid & 7, j5 = bid >> 3;          // 32 blocks per XCD
    int m0 = (xcd * 4 + (j5 & 3)) * 128;
    int n0 = (j5 >> 2) * 128;
    f32x4 acc[4][4];
    #pragma unroll
    for (int i = 0; i < 4; i++)
        #pragma unroll
        for (int j = 0; j < 4; j++)
            acc[i][j] = (f32x4){0.f, 0.f, 0.f, 0.f};

    mfma_gemm_128(Ab, Wb, m0, n0, tid, lA, lB, acc);

    #pragma unroll
    for (int fm = 0; fm < 4; fm++)
        #pragma unroll
        for (int reg = 0; reg < 4; reg++) {
            int m = m0 + wm * 64 + fm * 16 + lhi * 4 + reg;
            #pragma unroll
            for (int fn = 0; fn < 4; fn++) {
                int n = n0 + wn * 64 + fn * 16 + lane15;
                out[(long)m * HDIM + n] = acc[fm][fn][reg] + bo[n];
            }
        }
}

extern "C" void kernel_launch(void* const* d_in, const int* in_sizes, int n_in,
                              void* d_out, int out_size, void* d_ws, size_t ws_size,
                              hipStream_t stream) {
    const float* hs = (const float*)d_in[0];
    const float* wq = (const float*)d_in[2];
    const float* bq = (const float*)d_in[3];
    const float* wk = (const float*)d_in[4];
    const float* bk = (const float*)d_in[5];
    const float* wv = (const float*)d_in[6];
    const float* bv = (const float*)d_in[7];
    const float* wo = (const float*)d_in[8];
    const float* bo = (const float*)d_in[9];
    float* out = (float*)d_out;

    char* ws = (char*)d_ws;
    unsigned short* Xb    = (unsigned short*)(ws);                    // 8 MB
    unsigned short* Wqkv  = (unsigned short*)(ws + (8l  << 20));      // 6 MB
    unsigned short* Wob   = (unsigned short*)(ws + (14l << 20));      // 2 MB
    float2*         cstab = (float2*)        (ws + (16l << 20));      // 512 KB
    unsigned short* qbuf  = (unsigned short*)(ws + (17l << 20));      // 8 MB
    unsigned short* kbuf  = (unsigned short*)(ws + (25l << 20));      // 8 MB
    unsigned short* vbuf  = (unsigned short*)(ws + (33l << 20));      // 8 MB  (holds V^T [B,NH,HD,S])
    unsigned short* ctxb  = (unsigned short*)(ws + (41l << 20));      // 8 MB

    prep_kernel<<<8448, 256, 0, stream>>>(hs, wq, wk, wv, wo, Xb, Wqkv, Wob, cstab);
    gemm_qkv_kernel<<<768, 256, 0, stream>>>(Xb, Wqkv, bq, bk, bv, cstab, qbuf, kbuf, vbuf);
    attn_kernel<<<512, 512, 0, stream>>>(qbuf, kbuf, vbuf, ctxb);
    gemm_o_kernel<<<256, 256, 0, stream>>>(ctxb, Wob, bo, out);
}

// Round 14
// 98.138 us; speedup vs baseline: 1.1556x; 1.0384x over previous
//
#include <hip/hip_runtime.h>

#define BATCH 2
#define SDIM 2048
#define HDIM 1024
#define NHEADS 16
#define HEADD 64
#define WIN 1024

typedef __bf16 bf16x8 __attribute__((ext_vector_type(8)));
typedef __bf16 bf16x4 __attribute__((ext_vector_type(4)));
typedef float f32x4 __attribute__((ext_vector_type(4)));
typedef unsigned short u16x8 __attribute__((ext_vector_type(8)));

__device__ __forceinline__ unsigned short bf16_rne(float f) {
    union { float f; unsigned u; } x; x.f = f;
    unsigned r = x.u + 0x7fffu + ((x.u >> 16) & 1u);
    return (unsigned short)(r >> 16);
}

__device__ __forceinline__ void gload_lds16(const unsigned short* g, unsigned short* l) {
    __builtin_amdgcn_global_load_lds(
        (const __attribute__((address_space(1))) void*)g,
        (__attribute__((address_space(3))) void*)l, 16, 0, 0);
}

// ---------------- fused prep: f32->bf16 converts + RoPE table ----------------
__global__ __launch_bounds__(256) void prep_kernel(
    const float* __restrict__ hs, const float* __restrict__ wq, const float* __restrict__ wk,
    const float* __restrict__ wv, const float* __restrict__ wo,
    unsigned short* __restrict__ Xb, unsigned short* __restrict__ Wqkv,
    unsigned short* __restrict__ Wob, float2* __restrict__ cstab)
{
    int i = blockIdx.x * 256 + threadIdx.x;
    if (i < 2097152) {
        const float* src; unsigned short* dst; int off;
        if (i < 1048576)      { src = hs; dst = Xb;             off = i; }
        else if (i < 1310720) { src = wq; dst = Wqkv;           off = i - 1048576; }
        else if (i < 1572864) { src = wk; dst = Wqkv + 1048576; off = i - 1310720; }
        else if (i < 1835008) { src = wv; dst = Wqkv + 2097152; off = i - 1572864; }
        else                  { src = wo; dst = Wob;            off = i - 1835008; }
        float4 v = reinterpret_cast<const float4*>(src)[off];
        ushort4 r;
        r.x = bf16_rne(v.x); r.y = bf16_rne(v.y); r.z = bf16_rne(v.z); r.w = bf16_rne(v.w);
        reinterpret_cast<ushort4*>(dst)[off] = r;
    } else {
        int j = i - 2097152;                 // < 65536
        int p = j >> 5, f = j & 31;
        float inv = (float)pow(10000.0, -(double)f / 32.0);
        float ang = (float)p * inv;
        cstab[j] = make_float2(cosf(ang), sinf(ang));
    }
}

// ---------------- fused QKV projection + bias + RoPE + V-transpose (R11/R13 exact) ----------------
// 2-buffer ring (32 KB LDS): stage t+2 into buf(t) after compute barrier; vmcnt(4) counted,
// never drains mid-loop. V blocks write V^T directly via a 32 KB XOR-swizzled LDS transpose
// tile (reuses the full staging smem). FROZEN: epilogue edits perturb mainloop codegen (R12).
__global__ __launch_bounds__(256) void gemm_qkv_kernel(
    const unsigned short* __restrict__ Xb,
    const unsigned short* __restrict__ Wb,
    const float* __restrict__ bq, const float* __restrict__ bk, const float* __restrict__ bv,
    const float2* __restrict__ cstab,
    unsigned short* __restrict__ qbuf, unsigned short* __restrict__ kbuf, unsigned short* __restrict__ vbuf)
{
    const int K = 1024;
    const int BUF = 128 * 32;
    __shared__ __align__(16) unsigned short smem[4 * 128 * 32];   // 32 KB: lA 2 bufs | lB 2 bufs
    unsigned short* lA = smem;
    unsigned short* lB = smem + 2 * BUF;
    int tid = threadIdx.x;
    int lane = tid & 63, wid = tid >> 6;
    int wm = wid >> 1, wn = wid & 1;
    int lane15 = lane & 15, lhi = lane >> 4;
    int bid = blockIdx.x;
    int xcd = bid & 7, j5 = bid >> 3;          // 96 blocks per XCD
    int m0 = (xcd * 4 + (j5 & 3)) * 128;       // 4 X panels per XCD (L2-resident)
    int n0 = (j5 >> 2) * 128;                  // 24 W strips, streamed n-outer
    int lrow = lane >> 2;
    int swz = (lane & 3) ^ ((lane >> 3) & 3);
    const unsigned short* ga0 = Xb + (long)(m0 + wid * 32      + lrow) * K + swz * 8;
    const unsigned short* ga1 = Xb + (long)(m0 + wid * 32 + 16 + lrow) * K + swz * 8;
    const unsigned short* gb0 = Wb + (long)(n0 + wid * 32      + lrow) * K + swz * 8;
    const unsigned short* gb1 = Wb + (long)(n0 + wid * 32 + 16 + lrow) * K + swz * 8;
    unsigned short* la0 = lA + (wid * 32)      * 32;
    unsigned short* la1 = lA + (wid * 32 + 16) * 32;
    unsigned short* lb0 = lB + (wid * 32)      * 32;
    unsigned short* lb1 = lB + (wid * 32 + 16) * 32;
    int ru = (lhi ^ ((lane15 >> 1) & 3)) * 8;

    f32x4 acc[4][4];
    #pragma unroll
    for (int i = 0; i < 4; i++)
        #pragma unroll
        for (int j = 0; j < 4; j++)
            acc[i][j] = (f32x4){0.f, 0.f, 0.f, 0.f};

#define STAGE_Q(boff, kt) \
    gload_lds16(ga0 + (kt) * 32, la0 + (boff)); \
    gload_lds16(ga1 + (kt) * 32, la1 + (boff)); \
    gload_lds16(gb0 + (kt) * 32, lb0 + (boff)); \
    gload_lds16(gb1 + (kt) * 32, lb1 + (boff));

#define COMPUTE_Q(off) { \
    bf16x8 af[4], bfr[4]; \
    _Pragma("unroll") \
    for (int f = 0; f < 4; f++) { \
        af[f]  = *(const bf16x8*)&lA[(off) + (wm * 64 + f * 16 + lane15) * 32 + ru]; \
        bfr[f] = *(const bf16x8*)&lB[(off) + (wn * 64 + f * 16 + lane15) * 32 + ru]; \
    } \
    _Pragma("unroll") \
    for (int i = 0; i < 4; i++) \
        _Pragma("unroll") \
        for (int j = 0; j < 4; j++) \
            acc[i][j] = __builtin_amdgcn_mfma_f32_16x16x32_bf16(af[i], bfr[j], acc[i][j], 0, 0, 0); \
}

#define WAITQ(n) \
    asm volatile("s_waitcnt vmcnt(" #n ")" ::: "memory"); \
    __builtin_amdgcn_s_barrier(); \
    asm volatile("" ::: "memory");

    STAGE_Q(0, 0);
    STAGE_Q(BUF, 1);
    #pragma unroll 1
    for (int t = 0; t < 30; t += 2) {
        WAITQ(4);                       // tile t landed; t+1 in flight
        COMPUTE_Q(0);
        __builtin_amdgcn_s_barrier();   // all waves done reading buf0
        STAGE_Q(0, t + 2);
        WAITQ(4);                       // tile t+1 landed; t+2 in flight
        COMPUTE_Q(BUF);
        __builtin_amdgcn_s_barrier();   // all waves done reading buf1
        STAGE_Q(BUF, t + 3);
    }
    WAITQ(4);                           // tile 30 landed
    COMPUTE_Q(0);
    WAITQ(0);                           // tile 31 landed (only final drain)
    COMPUTE_Q(BUF);

#undef STAGE_Q
#undef COMPUTE_Q
#undef WAITQ

    int proj = n0 >> 10;                       // 0=q 1=k 2=v
    int ncol0 = (n0 & 1023) + wn * 64;
    int h = ncol0 >> 6;
    int bb = m0 >> 11, s0r = m0 & (SDIM - 1);  // block is within one batch (128 | 2048)
    if (proj == 2) {
        // V: bias-add -> swizzled LDS [d][s] tile (32 KB, full smem) -> coalesced V^T stores
        const float* bias = bv;
        __syncthreads();                       // mainloop LDS reads complete in all waves
        #pragma unroll
        for (int fm = 0; fm < 4; fm++)
            #pragma unroll
            for (int reg = 0; reg < 4; reg++) {
                int sl = wm * 64 + fm * 16 + lhi * 4 + reg;      // s within tile
                #pragma unroll
                for (int fn = 0; fn < 4; fn++) {
                    int dl = wn * 64 + fn * 16 + lane15;         // d within 128 (2 heads)
                    float v = acc[fm][fn][reg] + bias[(n0 & 1023) + dl];
                    smem[dl * 128 + (sl ^ ((dl & 7) * 8))] = bf16_rne(v);
                }
            }
        __syncthreads();
        int h0 = (n0 & 1023) >> 6;
        #pragma unroll
        for (int it = 0; it < 8; it++) {
            int d = it * 16 + (tid >> 4);
            int s8 = tid & 15;
            u16x8 valv = *(const u16x8*)&smem[d * 128 + ((s8 ^ (d & 7)) * 8)];
            int hh = h0 + (d >> 6);
            *(u16x8*)&vbuf[((long)(bb * NHEADS + hh) * HEADD + (d & 63)) * SDIM + s0r + s8 * 8] = valv;
        }
    } else {
        unsigned short* dst = proj == 0 ? qbuf : kbuf;
        const float* bias = proj == 0 ? bq : bk;
        #pragma unroll
        for (int fm = 0; fm < 4; fm++) {
            #pragma unroll
            for (int reg = 0; reg < 4; reg++) {
                int m = m0 + wm * 64 + fm * 16 + lhi * 4 + reg;
                int s = m & (SDIM - 1);
                long base = ((long)(bb * NHEADS + h) * SDIM + s) * HEADD;
                #pragma unroll
                for (int fn = 0; fn < 2; fn++) {
                    int j = fn * 16 + lane15;
                    float lo = acc[fm][fn][reg]     + bias[ncol0 + j];
                    float hi = acc[fm][fn + 2][reg] + bias[ncol0 + 32 + j];
                    float2 cs = cstab[s * 32 + j];
                    float rl = lo * cs.x - hi * cs.y;
                    float rh = hi * cs.x + lo * cs.y;
                    if (proj == 0) { rl *= 0.125f; rh *= 0.125f; }
                    dst[base + j]      = bf16_rne(rl);
                    dst[base + 32 + j] = bf16_rne(rh);
                }
            }
        }
    }
}

// ---------------- flash attention: QBLK=128 (8 waves x 16 rows), no-max softmax ----------------
// q/k: [B,NH,S,HD] bf16 (q pre-scaled by 1/8). vT: [B,NH,HD,S]. ctx out: [B,S,NH,HD] bf16.
// R13 structure (setprio around MFMA clusters). FROZEN.
__global__ __launch_bounds__(512) void attn_kernel(
    const unsigned short* __restrict__ qb,
    const unsigned short* __restrict__ kbf,
    const unsigned short* __restrict__ vtb,
    unsigned short* __restrict__ ctxb)
{
    __shared__ __align__(16) unsigned short Kl[64 * 72];
    __shared__ __align__(16) unsigned short Vl[64 * 72];   // rows = d, cols = s
    __shared__ __align__(16) unsigned short Pl[8][16 * 72];
    int tid = threadIdx.x, lane = tid & 63, wid = tid >> 6;   // 8 waves
    int lane15 = lane & 15, lhi = lane >> 4;

    int slot = blockIdx.x;            // 0..511
    int xcd = slot & 7;
    int pos = slot >> 3;              // 0..63
    int hb32 = xcd + 8 * (pos >> 4);  // 0..31
    int h = hb32 & 15, b = hb32 >> 4;
    int qt = 15 - (pos & 15);
    int q0b = qt * 128;
    int qw = q0b + wid * 16;          // this wave's 16 q-rows

    long hb = (long)(b * NHEADS + h) * SDIM * HEADD;
    const unsigned short* qptr = qb + hb;
    const unsigned short* kptr = kbf + hb;
    const unsigned short* vt   = vtb + hb;
    unsigned short* Pw = Pl[wid];

    bf16x8 aq0 = *(const bf16x8*)&qptr[(qw + lane15) * HEADD + lhi * 8];
    bf16x8 aq1 = *(const bf16x8*)&qptr[(qw + lane15) * HEADD + 32 + lhi * 8];

    f32x4 acc[4];
    #pragma unroll
    for (int f = 0; f < 4; f++) acc[f] = (f32x4){0.f, 0.f, 0.f, 0.f};
    float rs = 0.f;                   // lane-local partial sum for q = qw + lane15

    int t0 = q0b - (WIN - 1);
    int kb0 = t0 > 0 ? (t0 >> 6) : 0;
    int kbl = (q0b + 127) >> 6;       // = 2*qt + 1
    int srow = tid >> 3;              // 0..63
    int sc = (tid & 7) * 8;           // 16 B per thread

    u16x8 kr = *(const u16x8*)&kptr[(kb0 * 64 + srow) * HEADD + sc];
    u16x8 vr = *(const u16x8*)&vt[(long)srow * SDIM + kb0 * 64 + sc];

    for (int kblk = kb0; kblk <= kbl; kblk++) {
        int kbase = kblk * 64;
        __syncthreads();
        *(u16x8*)&Kl[srow * 72 + sc] = kr;
        *(u16x8*)&Vl[srow * 72 + sc] = vr;
        __syncthreads();
        if (kblk < kbl) {
            int nb = (kblk + 1) * 64;
            kr = *(const u16x8*)&kptr[(nb + srow) * HEADD + sc];
            vr = *(const u16x8*)&vt[(long)srow * SDIM + nb + sc];
        }
        if (kbase + 63 < qw - (WIN - 1)) continue;
        if (kbase > qw + 15) continue;

        bool full = (kbase + 63 <= qw) && (qw + 15 - kbase < WIN);
        f32x4 S[4];
        __builtin_amdgcn_s_setprio(1);
        #pragma unroll
        for (int fk = 0; fk < 4; fk++) {
            bf16x8 bk0 = *(const bf16x8*)&Kl[(fk * 16 + lane15) * 72 + lhi * 8];
            bf16x8 bk1 = *(const bf16x8*)&Kl[(fk * 16 + lane15) * 72 + 32 + lhi * 8];
            f32x4 s = (f32x4){0.f, 0.f, 0.f, 0.f};
            s = __builtin_amdgcn_mfma_f32_16x16x32_bf16(bk0, aq0, s, 0, 0, 0);
            s = __builtin_amdgcn_mfma_f32_16x16x32_bf16(bk1, aq1, s, 0, 0, 0);
            S[fk] = s;
        }
        __builtin_amdgcn_s_setprio(0);
        if (!full) {
            int q = qw + lane15;
            #pragma unroll
            for (int fk = 0; fk < 4; fk++)
                #pragma unroll
                for (int r = 0; r < 4; r++) {
                    int k = kbase + fk * 16 + lhi * 4 + r;
                    bool ok = (k <= q) && (q - k < WIN);
                    if (!ok) S[fk][r] = -1e30f;
                }
        }
        #pragma unroll
        for (int fk = 0; fk < 4; fk++) {
            bf16x4 c;
            #pragma unroll
            for (int r = 0; r < 4; r++) {
                float p = __expf(S[fk][r]);
                rs += p;
                c[r] = (__bf16)p;
            }
            *(bf16x4*)&Pw[lane15 * 72 + fk * 16 + lhi * 4] = c;
        }
        __builtin_amdgcn_s_setprio(1);
        #pragma unroll
        for (int ks = 0; ks < 2; ks++) {
            bf16x8 pa = *(const bf16x8*)&Pw[lane15 * 72 + ks * 32 + lhi * 8];
            #pragma unroll
            for (int fd = 0; fd < 4; fd++) {
                bf16x8 bv2 = *(const bf16x8*)&Vl[(fd * 16 + lane15) * 72 + ks * 32 + lhi * 8];
                acc[fd] = __builtin_amdgcn_mfma_f32_16x16x32_bf16(pa, bv2, acc[fd], 0, 0, 0);
            }
        }
        __builtin_amdgcn_s_setprio(0);
    }
    rs += __shfl_xor(rs, 16);
    rs += __shfl_xor(rs, 32);
    float linv[4];
    #pragma unroll
    for (int r = 0; r < 4; r++)
        linv[r] = 1.0f / __shfl(rs, lhi * 4 + r);
    #pragma unroll
    for (int fd = 0; fd < 4; fd++)
        #pragma unroll
        for (int r = 0; r < 4; r++) {
            int q = qw + lhi * 4 + r;
            int d = fd * 16 + lane15;
            ctxb[(((long)b * SDIM + q) * NHEADS + h) * HEADD + d] = bf16_rne(acc[fd][r] * linv[r]);
        }
}

// ---------------- output projection: out = ctx @ wo^T + bo (f32 out) ----------------
// 64x128 tile, 512 blocks = 2 blocks/CU (was 256 = 1/CU, 12.5% occupancy). B (Wob, 2 MB)
// is L2-resident so the extra B re-reads are cheap; A-panel traffic unchanged. Same XOR
// swizzle + 3-ring counted vmcnt(3) (3 loads/thread/step: A x1, B x2). Wave tile 32x64.
__global__ __launch_bounds__(256) void gemm_o_kernel(
    const unsigned short* __restrict__ Ab,
    const unsigned short* __restrict__ Wb,
    const float* __restrict__ bo,
    float* __restrict__ out)
{
    const int K = 1024;
    const int ABUF = 64 * 32;
    const int BBUF = 128 * 32;
    __shared__ __align__(16) unsigned short lA[3 * ABUF];   // 12 KB
    __shared__ __align__(16) unsigned short lB[3 * BBUF];   // 24 KB
    int tid = threadIdx.x;
    int lane = tid & 63, wid = tid >> 6;
    int wm = wid >> 1, wn = wid & 1;          // 2M x 2N waves, wave tile 32x64
    int lane15 = lane & 15, lhi = lane >> 4;
    int bid = blockIdx.x;
    int xcd = bid & 7, j6 = bid >> 3;         // 64 blocks per XCD
    int m0 = (xcd * 8 + (j6 & 7)) * 64;       // 8 A panels (1 MB) per XCD, L2-resident
    int n0 = (j6 >> 3) * 128;                 // 8 W strips, streamed n-outer
    int lrow = lane >> 2;
    int swz = (lane & 3) ^ ((lane >> 3) & 3);
    const unsigned short* ga0 = Ab + (long)(m0 + wid * 16      + lrow) * K + swz * 8;
    const unsigned short* gb0 = Wb + (long)(n0 + wid * 32      + lrow) * K + swz * 8;
    const unsigned short* gb1 = Wb + (long)(n0 + wid * 32 + 16 + lrow) * K + swz * 8;
    unsigned short* la0 = lA + (wid * 16)      * 32;
    unsigned short* lb0 = lB + (wid * 32)      * 32;
    unsigned short* lb1 = lB + (wid * 32 + 16) * 32;
    int ru = (lhi ^ ((lane15 >> 1) & 3)) * 8;

    f32x4 acc[2][4];
    #pragma unroll
    for (int i = 0; i < 2; i++)
        #pragma unroll
        for (int j = 0; j < 4; j++)
            acc[i][j] = (f32x4){0.f, 0.f, 0.f, 0.f};

#define STAGE_O(aoff, boff, kt) \
    gload_lds16(ga0 + (kt) * 32, la0 + (aoff)); \
    gload_lds16(gb0 + (kt) * 32, lb0 + (boff)); \
    gload_lds16(gb1 + (kt) * 32, lb1 + (boff));

#define COMPUTE_O(aoff, boff) { \
    bf16x8 af[2], bfr[4]; \
    _Pragma("unroll") \
    for (int f = 0; f < 2; f++) \
        af[f]  = *(const bf16x8*)&lA[(aoff) + (wm * 32 + f * 16 + lane15) * 32 + ru]; \
    _Pragma("unroll") \
    for (int f = 0; f < 4; f++) \
        bfr[f] = *(const bf16x8*)&lB[(boff) + (wn * 64 + f * 16 + lane15) * 32 + ru]; \
    _Pragma("unroll") \
    for (int i = 0; i < 2; i++) \
        _Pragma("unroll") \
        for (int j = 0; j < 4; j++) \
            acc[i][j] = __builtin_amdgcn_mfma_f32_16x16x32_bf16(af[i], bfr[j], acc[i][j], 0, 0, 0); \
}

#define WAITO(n) \
    asm volatile("s_waitcnt vmcnt(" #n ")" ::: "memory"); \
    __builtin_amdgcn_s_barrier(); \
    asm volatile("" ::: "memory");

    STAGE_O(0, 0, 0);
    STAGE_O(ABUF, BBUF, 1);
    #pragma unroll 1
    for (int t = 0; t < 30; t += 3) {
        WAITO(3);
        STAGE_O(2 * ABUF, 2 * BBUF, t + 2);
        COMPUTE_O(0, 0);
        WAITO(3);
        STAGE_O(0, 0, t + 3);
        COMPUTE_O(ABUF, BBUF);
        WAITO(3);
        STAGE_O(ABUF, BBUF, t + 4);
        COMPUTE_O(2 * ABUF, 2 * BBUF);
    }
    WAITO(3);
    COMPUTE_O(0, 0);
    WAITO(0);
    COMPUTE_O(ABUF, BBUF);

#undef STAGE_O
#undef COMPUTE_O
#undef WAITO

    #pragma unroll
    for (int fm = 0; fm < 2; fm++)
        #pragma unroll
        for (int reg = 0; reg < 4; reg++) {
            int m = m0 + wm * 32 + fm * 16 + lhi * 4 + reg;
            #pragma unroll
            for (int fn = 0; fn < 4; fn++) {
                int n = n0 + wn * 64 + fn * 16 + lane15;
                out[(long)m * HDIM + n] = acc[fm][fn][reg] + bo[n];
            }
        }
}

extern "C" void kernel_launch(void* const* d_in, const int* in_sizes, int n_in,
                              void* d_out, int out_size, void* d_ws, size_t ws_size,
                              hipStream_t stream) {
    const float* hs = (const float*)d_in[0];
    const float* wq = (const float*)d_in[2];
    const float* bq = (const float*)d_in[3];
    const float* wk = (const float*)d_in[4];
    const float* bk = (const float*)d_in[5];
    const float* wv = (const float*)d_in[6];
    const float* bv = (const float*)d_in[7];
    const float* wo = (const float*)d_in[8];
    const float* bo = (const float*)d_in[9];
    float* out = (float*)d_out;

    char* ws = (char*)d_ws;
    unsigned short* Xb    = (unsigned short*)(ws);                    // 8 MB
    unsigned short* Wqkv  = (unsigned short*)(ws + (8l  << 20));      // 6 MB
    unsigned short* Wob   = (unsigned short*)(ws + (14l << 20));      // 2 MB
    float2*         cstab = (float2*)        (ws + (16l << 20));      // 512 KB
    unsigned short* qbuf  = (unsigned short*)(ws + (17l << 20));      // 8 MB
    unsigned short* kbuf  = (unsigned short*)(ws + (25l << 20));      // 8 MB
    unsigned short* vbuf  = (unsigned short*)(ws + (33l << 20));      // 8 MB  (holds V^T [B,NH,HD,S])
    unsigned short* ctxb  = (unsigned short*)(ws + (41l << 20));      // 8 MB

    prep_kernel<<<8448, 256, 0, stream>>>(hs, wq, wk, wv, wo, Xb, Wqkv, Wob, cstab);
    gemm_qkv_kernel<<<768, 256, 0, stream>>>(Xb, Wqkv, bq, bk, bv, cstab, qbuf, kbuf, vbuf);
    attn_kernel<<<512, 512, 0, stream>>>(qbuf, kbuf, vbuf, ctxb);
    gemm_o_kernel<<<512, 256, 0, stream>>>(ctxb, Wob, bo, out);
}